// Round 1
// baseline (445.341 us; speedup 1.0000x reference)
//
#include <hip/hip_runtime.h>

#define B_SZ 32768
#define I_SZ 256
#define H_SZ 512
#define K_SZ 768   // I + H
#define NG   2048  // 4*H

typedef _Float16 half8 __attribute__((ext_vector_type(8)));
typedef _Float16 half4v __attribute__((ext_vector_type(4)));
typedef float f32x4 __attribute__((ext_vector_type(4)));

__device__ __forceinline__ float sigf(float x) {
  return __builtin_amdgcn_rcpf(1.0f + __builtin_amdgcn_exp2f(-1.44269504089f * x));
}
__device__ __forceinline__ float tanh_fast(float x) {
  return 1.0f - 2.0f * __builtin_amdgcn_rcpf(1.0f + __builtin_amdgcn_exp2f(2.88539008178f * x));
}

__device__ __forceinline__ void gl2lds16(const void* g, void* l) {
  __builtin_amdgcn_global_load_lds(
      (const __attribute__((address_space(1))) void*)g,
      (__attribute__((address_space(3))) void*)l, 16, 0, 0);
}

// ---------------- fused pre-pass (grid-stride, 2048 blocks x 256) ----------------
// Loop 1: pack A rows (f16 row-major [x|h]), 8 cols (16B store) per unit.
// Loop 2: pack W rows into MFMA-FRAGMENT order (same math as before), 4 cols per unit:
//     f = (((nb*2+wc)*12 + kb)*2 + ks)*4 + ni ; within f-block: lane(l4*16+l15)*8 + e
// Loop 3: bias sum.
__global__ void __launch_bounds__(256) prepass(const float* __restrict__ x,
                                               const float* __restrict__ h,
                                               const float* __restrict__ Wx,
                                               const float* __restrict__ Wh,
                                               const float* __restrict__ bx,
                                               const float* __restrict__ bh,
                                               _Float16* __restrict__ Aw,
                                               _Float16* __restrict__ Wf,
                                               float* __restrict__ bs) {
  const unsigned t = blockIdx.x * 256 + threadIdx.x;
  const unsigned nthr = gridDim.x * 256;

  // ---- A pack: B_SZ*96 octet units ----
  const unsigned NA = B_SZ * 96u;
  for (unsigned u = t; u < NA; u += nthr) {
    const unsigned r = u / 96u;        // magic-mul
    const unsigned co = u - r * 96u;   // octet index (0..95)
    float4 v0, v1;
    if (co < 32u) {
      const float* p = x + (size_t)r * I_SZ + co * 8u;
      v0 = *(const float4*)p; v1 = *(const float4*)(p + 4);
    } else {
      const float* p = h + (size_t)r * H_SZ + (co - 32u) * 8u;
      v0 = *(const float4*)p; v1 = *(const float4*)(p + 4);
    }
    half8 o = {(_Float16)v0.x, (_Float16)v0.y, (_Float16)v0.z, (_Float16)v0.w,
               (_Float16)v1.x, (_Float16)v1.y, (_Float16)v1.z, (_Float16)v1.w};
    *(half8*)(Aw + (size_t)u * 8) = o;
  }

  // ---- W pack: NG*192 quad units ----
  const unsigned NW = NG * 192u;
  for (unsigned u = t; u < NW; u += nthr) {
    const unsigned r = u / 192u;       // W row = gate*512 + j
    const unsigned q = u - r * 192u;   // quad index (0..191)
    const unsigned k = q * 4u;
    float4 v;
    if (k < 256u) v = *(const float4*)(Wx + (size_t)r * I_SZ + k);
    else          v = *(const float4*)(Wh + (size_t)r * H_SZ + (k - 256u));
    const unsigned g = r >> 9, j = r & 511u;
    const unsigned nb = j >> 5, jl = j & 31u;
    const unsigned cc = jl * 4u + g;   // tile col within 128-col block
    const unsigned wc = cc >> 6, ni = (cc >> 4) & 3u, l15 = cc & 15u;
    const unsigned kb = k >> 6, ks = (k >> 5) & 1u, l4 = (k >> 3) & 3u, e = k & 7u;
    const unsigned f = (((nb * 2u + wc) * 12u + kb) * 2u + ks) * 4u + ni;
    half4v o = {(_Float16)v.x, (_Float16)v.y, (_Float16)v.z, (_Float16)v.w};
    *(half4v*)(Wf + (size_t)f * 512 + (l4 * 16u + l15) * 8u + e) = o;
  }

  // ---- bias ----
  for (unsigned j = t; j < NG; j += nthr) bs[j] = bx[j] + bh[j];
}

// ---------------- main fused GEMM + LSTM epilogue ----------------
// 128x128 block tile, 4 waves 2x2, 16x16x32 f16 MFMA, BK=64.
// A: LDS double buffer (2x16KB), XOR-swizzled chunks, global_load_lds width 16,
//    ONE barrier per K-iter (prefetch issued right after barrier -> drain is free).
// W: no LDS — fragment-ordered global loads (L2-resident), REGISTER-PIPELINED one
//    full K-iter ahead so the L2 latency hides under the previous iter's MFMAs.
// blockIdx: XCD-aware remap so all 16 nb-blocks of an mb-panel land on one XCD's L2.
__global__ void __launch_bounds__(256) lstm_gemm(const _Float16* __restrict__ Aw,
                                                 const _Float16* __restrict__ Wf,
                                                 const float* __restrict__ bs,
                                                 const float* __restrict__ cIn,
                                                 float* __restrict__ outc,
                                                 float* __restrict__ outh) {
  __shared__ __align__(16) char smem[32768];

  const int t = threadIdx.x;
  const int lane = t & 63;
  const int wave = t >> 6;
  const int wr = wave >> 1, wc = wave & 1;
  const int l15 = lane & 15, l4 = lane >> 4;
  const int sw = l15 & 7;

  // XCD-aware swizzle: hw assigns XCD ~ bid%8. Give each XCD 32 contiguous
  // mb-panels; within an XCD iterate nb-major over groups of 8 mb so the
  // L2 working set stays ~8 panels (1.6 MB) + one W slice.
  const int bid0 = blockIdx.x;
  const int x8 = bid0 & 7;
  const int s = bid0 >> 3;            // 0..511
  const int mbg = s >> 7;             // 0..3
  const int rr = s & 127;
  const int nb = rr >> 3;             // 0..15
  const int mb = x8 * 32 + mbg * 8 + (rr & 7);
  const int j0 = nb * 32;
  const int m0 = mb * 128;

  // A staging: thread t -> row rA=t>>3 (of 32-row group q), chunk ct=t&7, XOR swizzle
  const int rA = t >> 3;
  const int colb = ((t & 7) ^ (rA & 7)) * 8;
  const size_t aBase = (size_t)(m0 + rA) * K_SZ + colb;

  // W fragment base for this (nb, wc): per (kb,ks,ni) offset (kb*8+ks*4+ni)*512
  const _Float16* wBase = Wf + (size_t)(nb * 2 + wc) * 96 * 512 + lane * 8;

  // init accumulators with bias
  f32x4 acc[4][4];
#pragma unroll
  for (int ni = 0; ni < 4; ++ni) {
    int tcol = wc * 64 + ni * 16 + l15;
    int gcol = (tcol & 3) * H_SZ + j0 + (tcol >> 2);
    float b = bs[gcol];
    f32x4 v = {b, b, b, b};
#pragma unroll
    for (int mi = 0; mi < 4; ++mi) acc[mi][ni] = v;
  }

  // prologue: stage kb=0 into buf0; preload W fragments for kb=0 (both ks)
#pragma unroll
  for (int q = 0; q < 4; ++q)
    gl2lds16(Aw + aBase + (size_t)q * 32 * K_SZ, smem + t * 16 + q * 4096);

  half8 wfA[4], wfB[4];
#pragma unroll
  for (int ni = 0; ni < 4; ++ni) {
    wfA[ni] = *(const half8*)(wBase + (size_t)(0 * 8 + 0 * 4 + ni) * 512);
    wfB[ni] = *(const half8*)(wBase + (size_t)(0 * 8 + 1 * 4 + ni) * 512);
  }

  for (int kb = 0; kb < K_SZ / 64; ++kb) {
    __syncthreads();  // vmcnt(0) drain covers loads issued one full iter ago
    if (kb < K_SZ / 64 - 1) {
      char* ldsNext = smem + ((kb + 1) & 1) * 16384 + t * 16;
#pragma unroll
      for (int q = 0; q < 4; ++q)
        gl2lds16(Aw + aBase + (size_t)q * 32 * K_SZ + (size_t)(kb + 1) * 64,
                 ldsNext + q * 4096);
    }
    const _Float16* As = (const _Float16*)(smem + (kb & 1) * 16384);
    half8 af[4];
    // ---- ks = 0 ----
#pragma unroll
    for (int mi = 0; mi < 4; ++mi)
      af[mi] = *(const half8*)(As + (wr * 64 + mi * 16 + l15) * 64 + ((l4 ^ sw) * 8));
#pragma unroll
    for (int mi = 0; mi < 4; ++mi)
#pragma unroll
      for (int ni = 0; ni < 4; ++ni)
        acc[mi][ni] = __builtin_amdgcn_mfma_f32_16x16x32_f16(af[mi], wfA[ni], acc[mi][ni], 0, 0, 0);
    if (kb < K_SZ / 64 - 1) {
#pragma unroll
      for (int ni = 0; ni < 4; ++ni)
        wfA[ni] = *(const half8*)(wBase + (size_t)((kb + 1) * 8 + 0 * 4 + ni) * 512);
    }
    // ---- ks = 1 ----
#pragma unroll
    for (int mi = 0; mi < 4; ++mi)
      af[mi] = *(const half8*)(As + (wr * 64 + mi * 16 + l15) * 64 + (((4 + l4) ^ sw) * 8));
#pragma unroll
    for (int mi = 0; mi < 4; ++mi)
#pragma unroll
      for (int ni = 0; ni < 4; ++ni)
        acc[mi][ni] = __builtin_amdgcn_mfma_f32_16x16x32_f16(af[mi], wfB[ni], acc[mi][ni], 0, 0, 0);
    if (kb < K_SZ / 64 - 1) {
#pragma unroll
      for (int ni = 0; ni < 4; ++ni)
        wfB[ni] = *(const half8*)(wBase + (size_t)((kb + 1) * 8 + 1 * 4 + ni) * 512);
    }
  }
  __syncthreads();  // K-loop reads done before epilogue reuses LDS

  // ---- epilogue: per-wave LDS transpose (stride 68 floats) ----
  // c is read once, outputs written once & never re-read -> nontemporal.
  float* T = (float*)(smem + wave * 8192);
#pragma unroll
  for (int mi = 0; mi < 4; ++mi) {
#pragma unroll
    for (int ni = 0; ni < 4; ++ni)
#pragma unroll
      for (int r = 0; r < 4; ++r)
        T[(l4 * 4 + r) * 68 + ni * 16 + l15] = acc[mi][ni][r];
#pragma unroll
    for (int orow = 0; orow < 4; ++orow) {
      int rloc = orow * 4 + l4;
      f32x4 gv = *(const f32x4*)(T + rloc * 68 + l15 * 4);
      int rowg = m0 + wr * 64 + mi * 16 + rloc;
      int jg = j0 + wc * 16 + l15;
      size_t off = (size_t)rowg * H_SZ + jg;
      float cv = __builtin_nontemporal_load(cIn + off);
      float it = sigf(gv[0]);
      float ft = sigf(gv[1]);
      float ot = sigf(gv[2]);
      float tc = tanh_fast(gv[3]);
      float ct = ft * cv + it * tc;
      float ht = ot * tanh_fast(ct);
      __builtin_nontemporal_store(ct, outc + off);
      __builtin_nontemporal_store(ht, outh + off);
    }
  }
}

// ---------------- fallback (ws too small): plain fp32 ----------------
__global__ void __launch_bounds__(256) lstm_naive(const float* __restrict__ x,
                                                  const float* __restrict__ h,
                                                  const float* __restrict__ c,
                                                  const float* __restrict__ Wx,
                                                  const float* __restrict__ bx,
                                                  const float* __restrict__ Wh,
                                                  const float* __restrict__ bh,
                                                  float* __restrict__ outc,
                                                  float* __restrict__ outh) {
  int idx = blockIdx.x * 256 + threadIdx.x;
  int b = idx >> 9, j = idx & 511;
  float gi = bx[j] + bh[j];
  float gf = bx[H_SZ + j] + bh[H_SZ + j];
  float go = bx[2 * H_SZ + j] + bh[2 * H_SZ + j];
  float gc = bx[3 * H_SZ + j] + bh[3 * H_SZ + j];
  const float* xr = x + (size_t)b * I_SZ;
  for (int k = 0; k < I_SZ; ++k) {
    float xv = xr[k];
    gi += xv * Wx[(size_t)j * I_SZ + k];
    gf += xv * Wx[(size_t)(H_SZ + j) * I_SZ + k];
    go += xv * Wx[(size_t)(2 * H_SZ + j) * I_SZ + k];
    gc += xv * Wx[(size_t)(3 * H_SZ + j) * I_SZ + k];
  }
  const float* hr = h + (size_t)b * H_SZ;
  for (int k = 0; k < H_SZ; ++k) {
    float hv = hr[k];
    gi += hv * Wh[(size_t)j * H_SZ + k];
    gf += hv * Wh[(size_t)(H_SZ + j) * H_SZ + k];
    go += hv * Wh[(size_t)(2 * H_SZ + j) * H_SZ + k];
    gc += hv * Wh[(size_t)(3 * H_SZ + j) * H_SZ + k];
  }
  float it = sigf(gi), ft = sigf(gf), ot = sigf(go), tc = tanh_fast(gc);
  float ct = ft * c[idx] + it * tc;
  outc[idx] = ct;
  outh[idx] = ot * tanh_fast(ct);
}

extern "C" void kernel_launch(void* const* d_in, const int* in_sizes, int n_in,
                              void* d_out, int out_size, void* d_ws, size_t ws_size,
                              hipStream_t stream) {
  const float* x  = (const float*)d_in[0];
  const float* h  = (const float*)d_in[1];
  const float* c  = (const float*)d_in[2];
  const float* Wx = (const float*)d_in[3];
  const float* bx = (const float*)d_in[4];
  const float* Wh = (const float*)d_in[5];
  const float* bh = (const float*)d_in[6];
  float* outc = (float*)d_out;
  float* outh = outc + (size_t)B_SZ * H_SZ;

  const size_t szA = (size_t)B_SZ * K_SZ * sizeof(_Float16);
  const size_t szW = (size_t)NG * K_SZ * sizeof(_Float16);
  const size_t need = szA + szW + (size_t)NG * sizeof(float);

  if (ws_size < need) {
    lstm_naive<<<(B_SZ * H_SZ) / 256, 256, 0, stream>>>(x, h, c, Wx, bx, Wh, bh, outc, outh);
    return;
  }

  _Float16* Aw = (_Float16*)d_ws;
  _Float16* Wf = (_Float16*)((char*)d_ws + szA);
  float* bs = (float*)((char*)d_ws + szA + szW);

  prepass<<<2048, 256, 0, stream>>>(x, h, Wx, Wh, bx, bh, Aw, Wf, bs);
  lstm_gemm<<<(B_SZ / 128) * (NG / 128), 256, 0, stream>>>(Aw, Wf, bs, c, outc, outh);
}

// Round 3
// 422.187 us; speedup vs baseline: 1.0548x; 1.0548x over previous
//
#include <hip/hip_runtime.h>

#define B_SZ 32768
#define I_SZ 256
#define H_SZ 512
#define K_SZ 768   // I + H
#define NG   2048  // 4*H

typedef _Float16 half8 __attribute__((ext_vector_type(8)));
typedef _Float16 half4v __attribute__((ext_vector_type(4)));
typedef float f32x4 __attribute__((ext_vector_type(4)));

__device__ __forceinline__ float sigf(float x) {
  return __builtin_amdgcn_rcpf(1.0f + __builtin_amdgcn_exp2f(-1.44269504089f * x));
}
__device__ __forceinline__ float tanh_fast(float x) {
  return 1.0f - 2.0f * __builtin_amdgcn_rcpf(1.0f + __builtin_amdgcn_exp2f(2.88539008178f * x));
}

__device__ __forceinline__ void gl2lds16(const void* g, void* l) {
  __builtin_amdgcn_global_load_lds(
      (const __attribute__((address_space(1))) void*)g,
      (__attribute__((address_space(3))) void*)l, 16, 0, 0);
}

// ---------------- fused pre-pass (grid-stride, 2048 blocks x 256) ----------------
// (verified passing in round 1; structurally independent of the gemm)
__global__ void __launch_bounds__(256) prepass(const float* __restrict__ x,
                                               const float* __restrict__ h,
                                               const float* __restrict__ Wx,
                                               const float* __restrict__ Wh,
                                               const float* __restrict__ bx,
                                               const float* __restrict__ bh,
                                               _Float16* __restrict__ Aw,
                                               _Float16* __restrict__ Wf,
                                               float* __restrict__ bs) {
  const unsigned t = blockIdx.x * 256 + threadIdx.x;
  const unsigned nthr = gridDim.x * 256;

  // ---- A pack: B_SZ*96 octet units ----
  const unsigned NA = B_SZ * 96u;
  for (unsigned u = t; u < NA; u += nthr) {
    const unsigned r = u / 96u;
    const unsigned co = u - r * 96u;
    float4 v0, v1;
    if (co < 32u) {
      const float* p = x + (size_t)r * I_SZ + co * 8u;
      v0 = *(const float4*)p; v1 = *(const float4*)(p + 4);
    } else {
      const float* p = h + (size_t)r * H_SZ + (co - 32u) * 8u;
      v0 = *(const float4*)p; v1 = *(const float4*)(p + 4);
    }
    half8 o = {(_Float16)v0.x, (_Float16)v0.y, (_Float16)v0.z, (_Float16)v0.w,
               (_Float16)v1.x, (_Float16)v1.y, (_Float16)v1.z, (_Float16)v1.w};
    *(half8*)(Aw + (size_t)u * 8) = o;
  }

  // ---- W pack: NG*192 quad units, MFMA-fragment order ----
  const unsigned NW = NG * 192u;
  for (unsigned u = t; u < NW; u += nthr) {
    const unsigned r = u / 192u;       // W row = gate*512 + j
    const unsigned q = u - r * 192u;
    const unsigned k = q * 4u;
    float4 v;
    if (k < 256u) v = *(const float4*)(Wx + (size_t)r * I_SZ + k);
    else          v = *(const float4*)(Wh + (size_t)r * H_SZ + (k - 256u));
    const unsigned g = r >> 9, j = r & 511u;
    const unsigned nb = j >> 5, jl = j & 31u;
    const unsigned cc = jl * 4u + g;
    const unsigned wc = cc >> 6, ni = (cc >> 4) & 3u, l15 = cc & 15u;
    const unsigned kb = k >> 6, ks = (k >> 5) & 1u, l4 = (k >> 3) & 3u, e = k & 7u;
    const unsigned f = (((nb * 2u + wc) * 12u + kb) * 2u + ks) * 4u + ni;
    half4v o = {(_Float16)v.x, (_Float16)v.y, (_Float16)v.z, (_Float16)v.w};
    *(half4v*)(Wf + (size_t)f * 512 + (l4 * 16u + l15) * 8u + e) = o;
  }

  // ---- bias ----
  for (unsigned j = t; j < NG; j += nthr) bs[j] = bx[j] + bh[j];
}

// ---------------- main fused GEMM + LSTM epilogue ----------------
// EXACT round-0 (verified 383us) loop/barrier/LDS structure. Only change:
// W register pipelining that cannot affect LDS ordering:
//   - wf(kb+1, ks=0) prefetched ONE FULL ITERATION early into static set wfN
//     (consumed next iter as wf0; barrier vmcnt(0) drain guarantees arrival)
//   - wf(kb, ks=1) loads hoisted ABOVE the ks=0 MFMA cluster (hidden under it)
// Wf/Aw are constant during this kernel, so W-load reordering is data-safe;
// the LDS read/write schedule is byte-identical to round-0.
__global__ void __launch_bounds__(256) lstm_gemm(const _Float16* __restrict__ Aw,
                                                 const _Float16* __restrict__ Wf,
                                                 const float* __restrict__ bs,
                                                 const float* __restrict__ cIn,
                                                 float* __restrict__ outc,
                                                 float* __restrict__ outh) {
  __shared__ __align__(16) char smem[32768];

  const int t = threadIdx.x;
  const int lane = t & 63;
  const int wave = t >> 6;
  const int wr = wave >> 1, wc = wave & 1;
  const int l15 = lane & 15, l4 = lane >> 4;
  const int sw = l15 & 7;

  const int bid = blockIdx.x;
  const int nb = bid & 15, mb = bid >> 4;   // 16 consecutive blocks share the A panel
  const int j0 = nb * 32;
  const int m0 = mb * 128;

  // A staging: thread t -> row rA=t>>3 (of 32-row group q), chunk ct=t&7, XOR swizzle
  const int rA = t >> 3;
  const int colb = ((t & 7) ^ (rA & 7)) * 8;
  const size_t aBase = (size_t)(m0 + rA) * K_SZ + colb;

  // W fragment base for this (nb, wc): per (kb,ks,ni) offset (kb*8+ks*4+ni)*512
  const _Float16* wBase = Wf + (size_t)(nb * 2 + wc) * 96 * 512 + lane * 8;

  // init accumulators with bias
  f32x4 acc[4][4];
#pragma unroll
  for (int ni = 0; ni < 4; ++ni) {
    int tcol = wc * 64 + ni * 16 + l15;
    int gcol = (tcol & 3) * H_SZ + j0 + (tcol >> 2);
    float b = bs[gcol];
    f32x4 v = {b, b, b, b};
#pragma unroll
    for (int mi = 0; mi < 4; ++mi) acc[mi][ni] = v;
  }

  // prologue: stage kb=0 into buf0; preload wf0 = W(kb=0, ks=0)
#pragma unroll
  for (int q = 0; q < 4; ++q)
    gl2lds16(Aw + aBase + (size_t)q * 32 * K_SZ, smem + t * 16 + q * 4096);

  half8 wf0[4], wf1[4], wfN[4];
#pragma unroll
  for (int ni = 0; ni < 4; ++ni)
    wf0[ni] = *(const half8*)(wBase + (size_t)ni * 512);

  for (int kb = 0; kb < K_SZ / 64; ++kb) {
    __syncthreads();  // vmcnt(0) drain covers loads issued one full iter ago
    if (kb < K_SZ / 64 - 1) {
      char* ldsNext = smem + ((kb + 1) & 1) * 16384 + t * 16;
#pragma unroll
      for (int q = 0; q < 4; ++q)
        gl2lds16(Aw + aBase + (size_t)q * 32 * K_SZ + (size_t)(kb + 1) * 64,
                 ldsNext + q * 4096);
    }
    const _Float16* As = (const _Float16*)(smem + (kb & 1) * 16384);
    half8 af[4];
    // ---- ks = 0: wf0 was prefetched last iteration (landed at barrier drain) ----
#pragma unroll
    for (int mi = 0; mi < 4; ++mi)
      af[mi] = *(const half8*)(As + (wr * 64 + mi * 16 + l15) * 64 + ((l4 ^ sw) * 8));
    // issue ks=1 W loads + next-iter ks=0 W prefetch BEFORE the MFMA cluster
#pragma unroll
    for (int ni = 0; ni < 4; ++ni)
      wf1[ni] = *(const half8*)(wBase + (size_t)(kb * 8 + 4 + ni) * 512);
    if (kb < K_SZ / 64 - 1) {
#pragma unroll
      for (int ni = 0; ni < 4; ++ni)
        wfN[ni] = *(const half8*)(wBase + (size_t)((kb + 1) * 8 + ni) * 512);
    }
#pragma unroll
    for (int mi = 0; mi < 4; ++mi)
#pragma unroll
      for (int ni = 0; ni < 4; ++ni)
        acc[mi][ni] = __builtin_amdgcn_mfma_f32_16x16x32_f16(af[mi], wf0[ni], acc[mi][ni], 0, 0, 0);
    // ---- ks = 1 ----
#pragma unroll
    for (int mi = 0; mi < 4; ++mi)
      af[mi] = *(const half8*)(As + (wr * 64 + mi * 16 + l15) * 64 + (((4 + l4) ^ sw) * 8));
#pragma unroll
    for (int mi = 0; mi < 4; ++mi)
#pragma unroll
      for (int ni = 0; ni < 4; ++ni)
        acc[mi][ni] = __builtin_amdgcn_mfma_f32_16x16x32_f16(af[mi], wf1[ni], acc[mi][ni], 0, 0, 0);
    // rotate prefetched set into wf0 (static indices -> pure register renames)
    if (kb < K_SZ / 64 - 1) {
#pragma unroll
      for (int ni = 0; ni < 4; ++ni) wf0[ni] = wfN[ni];
    }
  }
  __syncthreads();  // K-loop reads done before epilogue reuses LDS

  // ---- epilogue: per-wave LDS transpose (stride 68 floats) ----
  float* T = (float*)(smem + wave * 8192);
#pragma unroll
  for (int mi = 0; mi < 4; ++mi) {
#pragma unroll
    for (int ni = 0; ni < 4; ++ni)
#pragma unroll
      for (int r = 0; r < 4; ++r)
        T[(l4 * 4 + r) * 68 + ni * 16 + l15] = acc[mi][ni][r];
#pragma unroll
    for (int orow = 0; orow < 4; ++orow) {
      int rloc = orow * 4 + l4;
      f32x4 gv = *(const f32x4*)(T + rloc * 68 + l15 * 4);
      int rowg = m0 + wr * 64 + mi * 16 + rloc;
      int jg = j0 + wc * 16 + l15;
      size_t off = (size_t)rowg * H_SZ + jg;
      float cv = cIn[off];
      float it = sigf(gv[0]);
      float ft = sigf(gv[1]);
      float ot = sigf(gv[2]);
      float tc = tanh_fast(gv[3]);
      float ct = ft * cv + it * tc;
      float ht = ot * tanh_fast(ct);
      outc[off] = ct;
      outh[off] = ht;
    }
  }
}

// ---------------- fallback (ws too small): plain fp32 ----------------
__global__ void __launch_bounds__(256) lstm_naive(const float* __restrict__ x,
                                                  const float* __restrict__ h,
                                                  const float* __restrict__ c,
                                                  const float* __restrict__ Wx,
                                                  const float* __restrict__ bx,
                                                  const float* __restrict__ Wh,
                                                  const float* __restrict__ bh,
                                                  float* __restrict__ outc,
                                                  float* __restrict__ outh) {
  int idx = blockIdx.x * 256 + threadIdx.x;
  int b = idx >> 9, j = idx & 511;
  float gi = bx[j] + bh[j];
  float gf = bx[H_SZ + j] + bh[H_SZ + j];
  float go = bx[2 * H_SZ + j] + bh[2 * H_SZ + j];
  float gc = bx[3 * H_SZ + j] + bh[3 * H_SZ + j];
  const float* xr = x + (size_t)b * I_SZ;
  for (int k = 0; k < I_SZ; ++k) {
    float xv = xr[k];
    gi += xv * Wx[(size_t)j * I_SZ + k];
    gf += xv * Wx[(size_t)(H_SZ + j) * I_SZ + k];
    go += xv * Wx[(size_t)(2 * H_SZ + j) * I_SZ + k];
    gc += xv * Wx[(size_t)(3 * H_SZ + j) * I_SZ + k];
  }
  const float* hr = h + (size_t)b * H_SZ;
  for (int k = 0; k < H_SZ; ++k) {
    float hv = hr[k];
    gi += hv * Wh[(size_t)j * H_SZ + k];
    gf += hv * Wh[(size_t)(H_SZ + j) * H_SZ + k];
    go += hv * Wh[(size_t)(2 * H_SZ + j) * H_SZ + k];
    gc += hv * Wh[(size_t)(3 * H_SZ + j) * H_SZ + k];
  }
  float it = sigf(gi), ft = sigf(gf), ot = sigf(go), tc = tanh_fast(gc);
  float ct = ft * c[idx] + it * tc;
  outc[idx] = ct;
  outh[idx] = ot * tanh_fast(ct);
}

extern "C" void kernel_launch(void* const* d_in, const int* in_sizes, int n_in,
                              void* d_out, int out_size, void* d_ws, size_t ws_size,
                              hipStream_t stream) {
  const float* x  = (const float*)d_in[0];
  const float* h  = (const float*)d_in[1];
  const float* c  = (const float*)d_in[2];
  const float* Wx = (const float*)d_in[3];
  const float* bx = (const float*)d_in[4];
  const float* Wh = (const float*)d_in[5];
  const float* bh = (const float*)d_in[6];
  float* outc = (float*)d_out;
  float* outh = outc + (size_t)B_SZ * H_SZ;

  const size_t szA = (size_t)B_SZ * K_SZ * sizeof(_Float16);
  const size_t szW = (size_t)NG * K_SZ * sizeof(_Float16);
  const size_t need = szA + szW + (size_t)NG * sizeof(float);

  if (ws_size < need) {
    lstm_naive<<<(B_SZ * H_SZ) / 256, 256, 0, stream>>>(x, h, c, Wx, bx, Wh, bh, outc, outh);
    return;
  }

  _Float16* Aw = (_Float16*)d_ws;
  _Float16* Wf = (_Float16*)((char*)d_ws + szA);
  float* bs = (float*)((char*)d_ws + szA + szW);

  prepass<<<2048, 256, 0, stream>>>(x, h, Wx, Wh, bx, bh, Aw, Wf, bs);
  lstm_gemm<<<(B_SZ / 128) * (NG / 128), 256, 0, stream>>>(Aw, Wf, bs, c, outc, outh);
}

// Round 4
// 401.336 us; speedup vs baseline: 1.1096x; 1.0520x over previous
//
#include <hip/hip_runtime.h>

#define B_SZ 32768
#define I_SZ 256
#define H_SZ 512
#define K_SZ 768   // I + H
#define NG   2048  // 4*H

typedef _Float16 half8 __attribute__((ext_vector_type(8)));
typedef _Float16 half4v __attribute__((ext_vector_type(4)));
typedef float f32x4 __attribute__((ext_vector_type(4)));

__device__ __forceinline__ float sigf(float x) {
  return __builtin_amdgcn_rcpf(1.0f + __builtin_amdgcn_exp2f(-1.44269504089f * x));
}
__device__ __forceinline__ float tanh_fast(float x) {
  return 1.0f - 2.0f * __builtin_amdgcn_rcpf(1.0f + __builtin_amdgcn_exp2f(2.88539008178f * x));
}

// ---------------- fused pre-pass (grid-stride, 2048 blocks x 256) ----------------
// Loop 1: pack A into MFMA-FRAGMENT order (dest-ordered, coalesced 16B writes):
//   unit u -> lane=u&63, mi=(u>>6)&3, wr=(u>>8)&1, ks=(u>>9)&1, w3=u>>10,
//   kb=w3%12, mb=w3/12;  row r = mb*128+wr*64+mi*16+(u&15);
//   k = kb*64+ks*32+((u>>4)&3)*8;  Aw[u*8..+7] = (f16)A[r][k..k+7]
//   Gemm reads af[mi] = Aw + ((mb*192 + ((kb*2+ks)*2+wr)*4+mi)*64 + lane)*8 -> 1KB/wave coalesced.
// Loop 2: W pack, MFMA-fragment order (verified, unchanged).
// Loop 3: bias sum.
__global__ void __launch_bounds__(256) prepass(const float* __restrict__ x,
                                               const float* __restrict__ h,
                                               const float* __restrict__ Wx,
                                               const float* __restrict__ Wh,
                                               const float* __restrict__ bx,
                                               const float* __restrict__ bh,
                                               _Float16* __restrict__ Aw,
                                               _Float16* __restrict__ Wf,
                                               float* __restrict__ bs) {
  const unsigned t = blockIdx.x * 256 + threadIdx.x;
  const unsigned nthr = gridDim.x * 256;

  // ---- A fragment pack: B_SZ*96 octet units, dest-ordered ----
  const unsigned NA = B_SZ * 96u;
  for (unsigned u = t; u < NA; u += nthr) {
    const unsigned l15 = u & 15u;
    const unsigned l4 = (u >> 4) & 3u;
    const unsigned mi = (u >> 6) & 3u;
    const unsigned wr = (u >> 8) & 1u;
    const unsigned ks = (u >> 9) & 1u;
    const unsigned w3 = u >> 10;          // mb*12 + kb, < 3072
    const unsigned mb = w3 / 12u;         // magic-mul
    const unsigned kb = w3 - mb * 12u;
    const unsigned r = mb * 128u + wr * 64u + mi * 16u + l15;
    const unsigned k = kb * 64u + ks * 32u + l4 * 8u;
    float4 v0, v1;
    if (k < 256u) {
      const float* p = x + (size_t)r * I_SZ + k;
      v0 = *(const float4*)p; v1 = *(const float4*)(p + 4);
    } else {
      const float* p = h + (size_t)r * H_SZ + (k - 256u);
      v0 = *(const float4*)p; v1 = *(const float4*)(p + 4);
    }
    half8 o = {(_Float16)v0.x, (_Float16)v0.y, (_Float16)v0.z, (_Float16)v0.w,
               (_Float16)v1.x, (_Float16)v1.y, (_Float16)v1.z, (_Float16)v1.w};
    *(half8*)(Aw + (size_t)u * 8) = o;
  }

  // ---- W pack: NG*192 quad units, MFMA-fragment order ----
  const unsigned NW = NG * 192u;
  for (unsigned u = t; u < NW; u += nthr) {
    const unsigned r = u / 192u;       // W row = gate*512 + j
    const unsigned q = u - r * 192u;
    const unsigned k = q * 4u;
    float4 v;
    if (k < 256u) v = *(const float4*)(Wx + (size_t)r * I_SZ + k);
    else          v = *(const float4*)(Wh + (size_t)r * H_SZ + (k - 256u));
    const unsigned g = r >> 9, j = r & 511u;
    const unsigned nb = j >> 5, jl = j & 31u;
    const unsigned cc = jl * 4u + g;
    const unsigned wc = cc >> 6, ni = (cc >> 4) & 3u, l15 = cc & 15u;
    const unsigned kb = k >> 6, ks = (k >> 5) & 1u, l4 = (k >> 3) & 3u, e = k & 7u;
    const unsigned f = (((nb * 2u + wc) * 12u + kb) * 2u + ks) * 4u + ni;
    half4v o = {(_Float16)v.x, (_Float16)v.y, (_Float16)v.z, (_Float16)v.w};
    *(half4v*)(Wf + (size_t)f * 512 + (l4 * 16u + l15) * 8u + e) = o;
  }

  // ---- bias ----
  for (unsigned j = t; j < NG; j += nthr) bs[j] = bx[j] + bh[j];
}

// ---------------- main fused GEMM + LSTM epilogue ----------------
// 128x128 block tile, 4 waves 2x2, 16x16x32 f16 MFMA.
// BOTH operands in MFMA-fragment order in global memory (L2-resident working
// set ~390KB/block): K-loop is pure {coalesced dwordx4 loads -> MFMA}.
// ZERO LDS ops and ZERO __syncthreads in the entire kernel: no barrier drain,
// no convoy; per-wave stalls overlap across ~5 waves/SIMD and the compiler can
// pipeline the constant-memory loads freely. LDS used only for the per-wave
// (private region -> no barrier) epilogue gate transpose.
__global__ void __launch_bounds__(256) lstm_gemm(const _Float16* __restrict__ Aw,
                                                 const _Float16* __restrict__ Wf,
                                                 const float* __restrict__ bs,
                                                 const float* __restrict__ cIn,
                                                 float* __restrict__ outc,
                                                 float* __restrict__ outh) {
  __shared__ __align__(16) float Tbuf[4 * 1088];   // 4 waves x 16 rows x 68 floats

  const int t = threadIdx.x;
  const int lane = t & 63;
  const int wave = t >> 6;
  const int wr = wave >> 1, wc = wave & 1;
  const int l15 = lane & 15, l4 = lane >> 4;

  const int bid = blockIdx.x;
  const int nb = bid & 15, mb = bid >> 4;   // 16 consecutive blocks share the A panel
  const int j0 = nb * 32;
  const int m0 = mb * 128;

  // A fragment base for this (mb, wr): fragment stride 512 halves
  const _Float16* aBase = Aw + (size_t)mb * 192 * 512 + lane * 8;
  // W fragment base for this (nb, wc)
  const _Float16* wBase = Wf + (size_t)(nb * 2 + wc) * 96 * 512 + lane * 8;

  // init accumulators with bias
  f32x4 acc[4][4];
#pragma unroll
  for (int ni = 0; ni < 4; ++ni) {
    int tcol = wc * 64 + ni * 16 + l15;
    int gcol = (tcol & 3) * H_SZ + j0 + (tcol >> 2);
    float b = bs[gcol];
    f32x4 v = {b, b, b, b};
#pragma unroll
    for (int mi = 0; mi < 4; ++mi) acc[mi][ni] = v;
  }

  for (int kb = 0; kb < K_SZ / 64; ++kb) {
#pragma unroll
    for (int ks = 0; ks < 2; ++ks) {
      const int fi = ((kb * 2 + ks) * 2 + wr) * 4;
      half8 af[4], wf[4];
#pragma unroll
      for (int mi = 0; mi < 4; ++mi)
        af[mi] = *(const half8*)(aBase + (size_t)(fi + mi) * 512);
#pragma unroll
      for (int ni = 0; ni < 4; ++ni)
        wf[ni] = *(const half8*)(wBase + (size_t)(kb * 8 + ks * 4 + ni) * 512);
#pragma unroll
      for (int mi = 0; mi < 4; ++mi)
#pragma unroll
        for (int ni = 0; ni < 4; ++ni)
          acc[mi][ni] = __builtin_amdgcn_mfma_f32_16x16x32_f16(af[mi], wf[ni], acc[mi][ni], 0, 0, 0);
    }
  }

  // ---- epilogue: per-wave LDS transpose (stride 68 floats), wave-private ----
  float* T = Tbuf + wave * 1088;
#pragma unroll
  for (int mi = 0; mi < 4; ++mi) {
#pragma unroll
    for (int ni = 0; ni < 4; ++ni)
#pragma unroll
      for (int r = 0; r < 4; ++r)
        T[(l4 * 4 + r) * 68 + ni * 16 + l15] = acc[mi][ni][r];
#pragma unroll
    for (int orow = 0; orow < 4; ++orow) {
      int rloc = orow * 4 + l4;
      f32x4 gv = *(const f32x4*)(T + rloc * 68 + l15 * 4);
      int rowg = m0 + wr * 64 + mi * 16 + rloc;
      int jg = j0 + wc * 16 + l15;
      size_t off = (size_t)rowg * H_SZ + jg;
      float cv = cIn[off];
      float it = sigf(gv[0]);
      float ft = sigf(gv[1]);
      float ot = sigf(gv[2]);
      float tc = tanh_fast(gv[3]);
      float ct = ft * cv + it * tc;
      float ht = ot * tanh_fast(ct);
      outc[off] = ct;
      outh[off] = ht;
    }
  }
}

// ---------------- fallback (ws too small): plain fp32 ----------------
__global__ void __launch_bounds__(256) lstm_naive(const float* __restrict__ x,
                                                  const float* __restrict__ h,
                                                  const float* __restrict__ c,
                                                  const float* __restrict__ Wx,
                                                  const float* __restrict__ bx,
                                                  const float* __restrict__ Wh,
                                                  const float* __restrict__ bh,
                                                  float* __restrict__ outc,
                                                  float* __restrict__ outh) {
  int idx = blockIdx.x * 256 + threadIdx.x;
  int b = idx >> 9, j = idx & 511;
  float gi = bx[j] + bh[j];
  float gf = bx[H_SZ + j] + bh[H_SZ + j];
  float go = bx[2 * H_SZ + j] + bh[2 * H_SZ + j];
  float gc = bx[3 * H_SZ + j] + bh[3 * H_SZ + j];
  const float* xr = x + (size_t)b * I_SZ;
  for (int k = 0; k < I_SZ; ++k) {
    float xv = xr[k];
    gi += xv * Wx[(size_t)j * I_SZ + k];
    gf += xv * Wx[(size_t)(H_SZ + j) * I_SZ + k];
    go += xv * Wx[(size_t)(2 * H_SZ + j) * I_SZ + k];
    gc += xv * Wx[(size_t)(3 * H_SZ + j) * I_SZ + k];
  }
  const float* hr = h + (size_t)b * H_SZ;
  for (int k = 0; k < H_SZ; ++k) {
    float hv = hr[k];
    gi += hv * Wh[(size_t)j * H_SZ + k];
    gf += hv * Wh[(size_t)(H_SZ + j) * H_SZ + k];
    go += hv * Wh[(size_t)(2 * H_SZ + j) * H_SZ + k];
    gc += hv * Wh[(size_t)(3 * H_SZ + j) * H_SZ + k];
  }
  float it = sigf(gi), ft = sigf(gf), ot = sigf(go), tc = tanh_fast(gc);
  float ct = ft * c[idx] + it * tc;
  outc[idx] = ct;
  outh[idx] = ot * tanh_fast(ct);
}

extern "C" void kernel_launch(void* const* d_in, const int* in_sizes, int n_in,
                              void* d_out, int out_size, void* d_ws, size_t ws_size,
                              hipStream_t stream) {
  const float* x  = (const float*)d_in[0];
  const float* h  = (const float*)d_in[1];
  const float* c  = (const float*)d_in[2];
  const float* Wx = (const float*)d_in[3];
  const float* bx = (const float*)d_in[4];
  const float* Wh = (const float*)d_in[5];
  const float* bh = (const float*)d_in[6];
  float* outc = (float*)d_out;
  float* outh = outc + (size_t)B_SZ * H_SZ;

  const size_t szA = (size_t)B_SZ * K_SZ * sizeof(_Float16);
  const size_t szW = (size_t)NG * K_SZ * sizeof(_Float16);
  const size_t need = szA + szW + (size_t)NG * sizeof(float);

  if (ws_size < need) {
    lstm_naive<<<(B_SZ * H_SZ) / 256, 256, 0, stream>>>(x, h, c, Wx, bx, Wh, bh, outc, outh);
    return;
  }

  _Float16* Aw = (_Float16*)d_ws;
  _Float16* Wf = (_Float16*)((char*)d_ws + szA);
  float* bs = (float*)((char*)d_ws + szA + szW);

  prepass<<<2048, 256, 0, stream>>>(x, h, Wx, Wh, bx, bh, Aw, Wf, bs);
  lstm_gemm<<<(B_SZ / 128) * (NG / 128), 256, 0, stream>>>(Aw, Wf, bs, c, outc, outh);
}